// Round 7
// baseline (1112.941 us; speedup 1.0000x reference)
//
#include <hip/hip_runtime.h>

// Problem constants
#define B_SZ 512
#define T_SZ 512
#define I_SZ 256
#define H_SZ 250

typedef __bf16 bf16x8 __attribute__((ext_vector_type(8)));
typedef __bf16 bf16x4 __attribute__((ext_vector_type(4)));
typedef float  f32x4  __attribute__((ext_vector_type(4)));

__device__ __forceinline__ float fast_tanh(float x) {
    float ax = __builtin_fabsf(x);
    float e  = __expf(-2.0f * ax);          // v_exp_f32 path
    float r  = (1.0f - e) / (1.0f + e);
    return __builtin_copysignf(r, x);
}

// ---------------------------------------------------------------------------
// Kernel 1: xproj[b][t][j] = x[b][t][:] . Wx[j][:] + bh[j]   (written to out)
// M = B*T = 262144 rows, K = 256, N = 250 (padded to 256).
// NEW: single 128x256 tile per block (was 2 blocks of 128x128 sharing the
// same A-panel): x is now fetched from HBM exactly once (268 MB, was ~537),
// staging VALU per CU -25%, and 32 MFMA per wave per staged K-step (was 16).
// 2048 blocks, 256 threads / 4 waves (2x2 wave grid), LDS 30 KB -> 2 blk/CU.
// ---------------------------------------------------------------------------
#define BM 128
#define BN 256
#define BK 32
#define LDT 40   // LDS row stride in bf16 elems (80B, 16B-aligned)

__global__ __launch_bounds__(256, 2) void xproj_kernel(
    const float* __restrict__ x,    // [M][256]
    const float* __restrict__ Wx,   // [250][256]
    const float* __restrict__ bh,   // [250]
    float* __restrict__ out)        // [M][250]
{
    __shared__ __align__(16) __bf16 As[BM * LDT];   // 128 rows
    __shared__ __align__(16) __bf16 Bs[BN * LDT];   // 256 rows (N dim)

    const int m0 = blockIdx.x * BM;

    const int tid  = threadIdx.x;
    const int lane = tid & 63;
    const int wave = tid >> 6;
    const int wm   = wave >> 1;      // wave row (0/1) -> 64 rows
    const int wn   = wave & 1;       // wave col (0/1) -> 128 cols
    const int l15  = lane & 15;
    const int quad = lane >> 4;

    f32x4 acc[4][8];
#pragma unroll
    for (int i = 0; i < 4; ++i)
#pragma unroll
        for (int j = 0; j < 8; ++j)
            acc[i][j] = (f32x4){0.f, 0.f, 0.f, 0.f};

    for (int kk = 0; kk < I_SZ / BK; ++kk) {
        __syncthreads();   // previous iter's frag reads done
        // stage A (x): 128 rows x 32 k = 1024 float4, fp32 -> bf16
#pragma unroll
        for (int i = 0; i < 4; ++i) {
            int f   = tid + i * 256;
            int row = f >> 3;
            int c4  = f & 7;
            const float4 v = *(const float4*)&x[(size_t)(m0 + row) * I_SZ + kk * BK + c4 * 4];
            bf16x4 b;
            b[0] = (__bf16)v.x; b[1] = (__bf16)v.y; b[2] = (__bf16)v.z; b[3] = (__bf16)v.w;
            *(bf16x4*)&As[row * LDT + c4 * 4] = b;
        }
        // stage B (Wx): 256 rows (n) x 32 k = 2048 float4; rows >= 250 zero
#pragma unroll
        for (int i = 0; i < 8; ++i) {
            int f   = tid + i * 256;
            int row = f >> 3;
            int c4  = f & 7;
            bf16x4 b;
            if (row < H_SZ) {
                const float4 v = *(const float4*)&Wx[(size_t)row * I_SZ + kk * BK + c4 * 4];
                b[0] = (__bf16)v.x; b[1] = (__bf16)v.y; b[2] = (__bf16)v.z; b[3] = (__bf16)v.w;
            } else {
                b[0] = (__bf16)0.f; b[1] = (__bf16)0.f; b[2] = (__bf16)0.f; b[3] = (__bf16)0.f;
            }
            *(bf16x4*)&Bs[row * LDT + c4 * 4] = b;
        }
        __syncthreads();

        bf16x8 af[4], bfr[8];
#pragma unroll
        for (int tm = 0; tm < 4; ++tm)
            af[tm] = *(const bf16x8*)&As[(wm * 64 + tm * 16 + l15) * LDT + quad * 8];
#pragma unroll
        for (int tn = 0; tn < 8; ++tn)
            bfr[tn] = *(const bf16x8*)&Bs[(wn * 128 + tn * 16 + l15) * LDT + quad * 8];
#pragma unroll
        for (int tm = 0; tm < 4; ++tm)
#pragma unroll
            for (int tn = 0; tn < 8; ++tn)
                acc[tm][tn] = __builtin_amdgcn_mfma_f32_16x16x32_bf16(af[tm], bfr[tn], acc[tm][tn], 0, 0, 0);
    }

    // epilogue: C row = quad*4+reg (m), col = lane&15 (n); add bias
#pragma unroll
    for (int tn = 0; tn < 8; ++tn) {
        int gn = wn * 128 + tn * 16 + l15;
        if (gn >= H_SZ) continue;
        float bias = bh[gn];
#pragma unroll
        for (int tm = 0; tm < 4; ++tm) {
#pragma unroll
            for (int r = 0; r < 4; ++r) {
                int gm = m0 + wm * 64 + tm * 16 + quad * 4 + r;
                out[(size_t)gm * H_SZ + gn] = acc[tm][tn][r] + bias;
            }
        }
    }
}

// ---------------------------------------------------------------------------
// Kernel 2: recurrence. NEW: 512 blocks x 256 threads, ONE batch per block,
// 2 independent blocks per CU (2 barrier groups -> stalls of one overlap
// compute of the other; attacks the measured latency-bound profile:
// Occ 22.8% with MfmaUtil 27.8% / VALUBusy 31%).
//  - j-split 4 ways: wave owns 64 cols (4 n-tiles); Wh B-frags in registers
//    (wf[4][8], 128 VGPRs)
//  - hbuf kt-interleaved + CONFLICT-FREE (measured 3.565e7 bank-conflict
//    cycles/dispatch in previous layout): elem = kt*64 + sel*32 + quad*8 + e,
//    sel 0 = h row (lane l15==0), sel 1 = permanent zero row (l15>0,
//    broadcast). Per ds_read_b128: h-lanes hit banks 0-15, zero-lanes hit
//    banks 16-31 -> zero conflicts for every kt.
//  - xproj prefetched two steps ahead; 8 accumulator chains (2 per n-tile)
//  - step barrier = s_waitcnt lgkmcnt(0) + raw s_barrier (no vmcnt drain on
//    the 512-step critical path)
// ---------------------------------------------------------------------------
__global__ __launch_bounds__(256, 2) void rnn_kernel(
    const float* __restrict__ h0,   // [B][250]
    const float* __restrict__ Wh,   // [250][250]
    float* __restrict__ out)        // [B][T][250], pre-filled with xproj+bias
{
    // [buf][kt*64 + sel*32 + quad*8 + e] elems; 2 KB total
    __shared__ __align__(16) __bf16 hbuf[2][512];

    const int b    = blockIdx.x;          // one batch per block
    const int tid  = threadIdx.x;
    const int lane = tid & 63;
    const int wave = tid >> 6;            // 0..3
    const int l15  = lane & 15;
    const int quad = lane >> 4;           // 0..3
    const int j0w  = wave * 64;           // 64 cols per wave

    // zero both buffers (zero slots + k>=250 padding stay 0 forever)
    for (int i = tid; i < 2 * 512; i += 256)
        ((__bf16*)hbuf)[i] = (__bf16)0.f;
    __syncthreads();

    // init h into buf0 h-slots: k -> elem (k>>5)*64 + ((k>>3)&3)*8 + (k&7)
    for (int k = tid; k < H_SZ; k += 256) {
        int e = ((k >> 5) << 6) + (((k >> 3) & 3) << 3) + (k & 7);
        hbuf[0][e] = (__bf16)h0[(size_t)b * H_SZ + k];
    }

    // Wh fragments in registers: wf[tl][kt], B-frag layout
    // B[k = quad*8+e][n = l15]; n = j0w + tl*16 + l15, k = kt*32 + quad*8 + e
    // B[k][n] = Wh[n][k]  (recurrence needs sum_k h[k] * Wh[j][k])
    bf16x8 wf[4][8];
#pragma unroll
    for (int tl = 0; tl < 4; ++tl) {
        const int j = j0w + tl * 16 + l15;
#pragma unroll
        for (int kt = 0; kt < 8; ++kt) {
            const int kb = kt * 32 + quad * 8;
            bf16x8 v;
#pragma unroll
            for (int e = 0; e < 8; ++e) {
                const int k = kb + e;
                v[e] = (j < H_SZ && k < H_SZ) ? (__bf16)Wh[(size_t)j * H_SZ + k] : (__bf16)0.f;
            }
            wf[tl][kt] = v;
        }
    }
    __syncthreads();

    // A-frag: lane l15 supplies matrix row m = l15; only row 0 (the batch)
    // is nonzero, rows 1..15 read the zero half of the kt block (broadcast).
    const int aoff = (l15 == 0) ? 0 : 32;   // elems within kt-block

    bool   act[4];
    int    jj[4];
    int    we[4];       // hbuf write elem offset for this thread's j
    float* xptr[4];
#pragma unroll
    for (int tl = 0; tl < 4; ++tl) {
        jj[tl]  = j0w + tl * 16 + l15;
        act[tl] = (quad == 0) && (jj[tl] < H_SZ);
        const int jc = (jj[tl] < H_SZ) ? jj[tl] : 0;   // keep addr in-range
        we[tl]  = ((jc >> 5) << 6) + (((jc >> 3) & 3) << 3) + (jc & 7);
        xptr[tl] = out + (size_t)b * T_SZ * H_SZ + jc;
    }

    // xproj shift register: xc = step t, x1 = step t+1 (distance-2 prefetch)
    float xc[4], x1[4];
#pragma unroll
    for (int tl = 0; tl < 4; ++tl) {
        xc[tl] = act[tl] ? xptr[tl][0]    : 0.f;
        x1[tl] = act[tl] ? xptr[tl][H_SZ] : 0.f;
    }

    for (int t = 0; t < T_SZ; ++t) {
        const int cur = t & 1;
        const int nxt = cur ^ 1;

        // prefetch xproj for t+2 (in flight across ~2 full steps)
        float x2[4];
        const bool pf = (t + 2 < T_SZ);
#pragma unroll
        for (int tl = 0; tl < 4; ++tl)
            x2[tl] = (pf && act[tl]) ? xptr[tl][2 * H_SZ] : 0.f;

        // A fragments: conflict-free kt-interleaved read (16B aligned)
        bf16x8 af[8];
#pragma unroll
        for (int kt = 0; kt < 8; ++kt)
            af[kt] = *(const bf16x8*)&hbuf[cur][kt * 64 + aoff + quad * 8];

        // 8 independent accumulator chains (2 per n-tile, depth 4)
        f32x4 aA[4], aB[4];
#pragma unroll
        for (int tl = 0; tl < 4; ++tl) {
            aA[tl] = (f32x4){0.f, 0.f, 0.f, 0.f};
            aB[tl] = (f32x4){0.f, 0.f, 0.f, 0.f};
        }
#pragma unroll
        for (int kt = 0; kt < 4; ++kt) {
#pragma unroll
            for (int tl = 0; tl < 4; ++tl) {
                aA[tl] = __builtin_amdgcn_mfma_f32_16x16x32_bf16(af[kt],     wf[tl][kt],     aA[tl], 0, 0, 0);
                aB[tl] = __builtin_amdgcn_mfma_f32_16x16x32_bf16(af[kt + 4], wf[tl][kt + 4], aB[tl], 0, 0, 0);
            }
        }

        // epilogue: C row (m=batch) = quad*4 + r -> batch at quad0, r0;
        // col (n=j) = lane&15
#pragma unroll
        for (int tl = 0; tl < 4; ++tl) {
            const float s = aA[tl][0] + aB[tl][0];
            if (act[tl]) {
                float v = fast_tanh(s + xc[tl]);
                xptr[tl][0] = v;                       // overwrite xproj with state
                hbuf[nxt][we[tl]] = (__bf16)v;         // h for next step
            }
            xptr[tl] += H_SZ;
            xc[tl] = x1[tl];
            x1[tl] = x2[tl];
        }

        // end-of-step sync: LDS ops drained, barrier WITHOUT vmcnt drain
        // (prefetch loads + global stores stay in flight)
        asm volatile("s_waitcnt lgkmcnt(0)" ::: "memory");
        __builtin_amdgcn_s_barrier();
        asm volatile("" ::: "memory");
    }
}

extern "C" void kernel_launch(void* const* d_in, const int* in_sizes, int n_in,
                              void* d_out, int out_size, void* d_ws, size_t ws_size,
                              hipStream_t stream) {
    const float* x  = (const float*)d_in[0];
    const float* h  = (const float*)d_in[1];
    const float* Wx = (const float*)d_in[2];
    const float* Wh = (const float*)d_in[3];
    const float* bh = (const float*)d_in[4];
    float* out = (float*)d_out;

    const int M = B_SZ * T_SZ;                 // 262144
    xproj_kernel<<<dim3(M / BM), dim3(256), 0, stream>>>(x, Wx, bh, out);
    rnn_kernel<<<dim3(B_SZ), dim3(256), 0, stream>>>(h, Wh, out);
}

// Round 8
// 933.371 us; speedup vs baseline: 1.1924x; 1.1924x over previous
//
#include <hip/hip_runtime.h>

// Problem constants
#define B_SZ 512
#define T_SZ 512
#define I_SZ 256
#define H_SZ 250

typedef __bf16 bf16x8 __attribute__((ext_vector_type(8)));
typedef __bf16 bf16x4 __attribute__((ext_vector_type(4)));
typedef float  f32x4  __attribute__((ext_vector_type(4)));

__device__ __forceinline__ float fast_tanh(float x) {
    float ax = __builtin_fabsf(x);
    float e  = __expf(-2.0f * ax);          // v_exp_f32 path
    float r  = (1.0f - e) / (1.0f + e);
    return __builtin_copysignf(r, x);
}

// ---------------------------------------------------------------------------
// Kernel 1 (restructured): xproj[m][j] = x[m][:] . Wx[j][:] + bh[j]
// Per block: 64 m-rows, ALL 250 j. A-panel staged ONCE (full K=256, bf16,
// stride 260 elems -> 130 dw = 2 mod 32: conflict-free frag reads). Wx
// streamed through LDS in four 64-k chunks (stride 68 elems -> 34 dw = 2
// mod 32), chunk c+1 staged before chunk c's MFMA burst (Wx is L2-hot:
// 256 KB reused by every block). 4 waves x 4 n-tiles, acc[4][4], 128 MFMA
// per wave between few barriers (9/block vs 8 full drains before).
// LDS 68 KB -> 2 blocks/CU.
// ---------------------------------------------------------------------------
#define XBM 64
#define LDA 260   // A stride (bf16 elems): 130 dwords == 2 mod 32
#define LWS 68    // W chunk stride (bf16 elems): 34 dwords == 2 mod 32

__global__ __launch_bounds__(256, 2) void xproj_kernel(
    const float* __restrict__ x,    // [M][256]
    const float* __restrict__ Wx,   // [250][256]
    const float* __restrict__ bh,   // [250]
    float* __restrict__ out)        // [M][250]
{
    __shared__ __align__(16) __bf16 As[XBM * LDA];   // 33,280 B
    __shared__ __align__(16) __bf16 Ws[256 * LWS];   // 34,816 B

    const int m0   = blockIdx.x * XBM;
    const int tid  = threadIdx.x;
    const int lane = tid & 63;
    const int wave = tid >> 6;       // 0..3
    const int l15  = lane & 15;
    const int quad = lane >> 4;
    const int j0w  = wave * 64;      // 64 cols per wave (4 n-tiles)

    // ---- stage A once: 64 rows x 256 k, fp32 -> bf16 (16 float4/thread)
#pragma unroll
    for (int i = 0; i < 16; ++i) {
        int f   = tid + i * 256;        // 0..4095, 64 float4 per row
        int row = f >> 6;
        int c4  = f & 63;
        const float4 v = *(const float4*)&x[(size_t)(m0 + row) * I_SZ + c4 * 4];
        bf16x4 b;
        b[0] = (__bf16)v.x; b[1] = (__bf16)v.y; b[2] = (__bf16)v.z; b[3] = (__bf16)v.w;
        *(bf16x4*)&As[row * LDA + c4 * 4] = b;
    }
    // ---- stage W chunk 0 (k 0..63): 256 rows x 64 k (16 float4/thread)
#pragma unroll
    for (int i = 0; i < 16; ++i) {
        int f   = tid + i * 256;        // 0..4095, 16 float4 per row
        int row = f >> 4;
        int c4  = f & 15;
        bf16x4 b;
        if (row < H_SZ) {
            const float4 v = *(const float4*)&Wx[(size_t)row * I_SZ + c4 * 4];
            b[0] = (__bf16)v.x; b[1] = (__bf16)v.y; b[2] = (__bf16)v.z; b[3] = (__bf16)v.w;
        } else {
            b[0] = (__bf16)0.f; b[1] = (__bf16)0.f; b[2] = (__bf16)0.f; b[3] = (__bf16)0.f;
        }
        *(bf16x4*)&Ws[row * LWS + c4 * 4] = b;
    }
    __syncthreads();

    f32x4 acc[4][4];   // [tm][tl]
#pragma unroll
    for (int a = 0; a < 4; ++a)
#pragma unroll
        for (int bq = 0; bq < 4; ++bq)
            acc[a][bq] = (f32x4){0.f, 0.f, 0.f, 0.f};

    for (int c = 0; c < 4; ++c) {
        // read this chunk's B-fragments into registers
        bf16x8 wf[4][2];
#pragma unroll
        for (int tl = 0; tl < 4; ++tl)
#pragma unroll
            for (int kt = 0; kt < 2; ++kt)
                wf[tl][kt] = *(const bf16x8*)&Ws[(j0w + tl * 16 + l15) * LWS + kt * 32 + quad * 8];
        __syncthreads();   // wf in regs (lgkm drained); Ws free for overwrite

        // stage next chunk (loads issue early, hide under MFMAs below)
        if (c < 3) {
#pragma unroll
            for (int i = 0; i < 16; ++i) {
                int f   = tid + i * 256;
                int row = f >> 4;
                int c4  = f & 15;
                bf16x4 b;
                if (row < H_SZ) {
                    const float4 v = *(const float4*)&Wx[(size_t)row * I_SZ + (c + 1) * 64 + c4 * 4];
                    b[0] = (__bf16)v.x; b[1] = (__bf16)v.y; b[2] = (__bf16)v.z; b[3] = (__bf16)v.w;
                } else {
                    b[0] = (__bf16)0.f; b[1] = (__bf16)0.f; b[2] = (__bf16)0.f; b[3] = (__bf16)0.f;
                }
                *(bf16x4*)&Ws[row * LWS + c4 * 4] = b;
            }
        }

        // compute this chunk: 4 m-tiles x 4 n-tiles x 2 kt = 32 MFMA/wave
#pragma unroll
        for (int tm = 0; tm < 4; ++tm) {
            bf16x8 af[2];
#pragma unroll
            for (int kt = 0; kt < 2; ++kt)
                af[kt] = *(const bf16x8*)&As[(tm * 16 + l15) * LDA + c * 64 + kt * 32 + quad * 8];
#pragma unroll
            for (int kt = 0; kt < 2; ++kt)
#pragma unroll
                for (int tl = 0; tl < 4; ++tl)
                    acc[tm][tl] = __builtin_amdgcn_mfma_f32_16x16x32_bf16(af[kt], wf[tl][kt], acc[tm][tl], 0, 0, 0);
        }
        __syncthreads();   // af reads + next-chunk writes drained for all waves
    }

    // epilogue: C row = quad*4+r (m), col = lane&15 (n); add bias
#pragma unroll
    for (int tl = 0; tl < 4; ++tl) {
        int gn = j0w + tl * 16 + l15;
        if (gn >= H_SZ) continue;
        float bias = bh[gn];
#pragma unroll
        for (int tm = 0; tm < 4; ++tm) {
#pragma unroll
            for (int r = 0; r < 4; ++r) {
                int gm = m0 + tm * 16 + quad * 4 + r;
                out[(size_t)gm * H_SZ + gn] = acc[tm][tl][r] + bias;
            }
        }
    }
}

// ---------------------------------------------------------------------------
// Kernel 2: recurrence. REVERT to round-6 two-batches-per-MFMA structure
// (408 µs measured; round 7's one-batch variant doubled MFMA work -> 624)
// + KEEP round 7's proven conflict-free kt-interleaved hbuf layout
// (SQ_LDS_BANK_CONFLICT measured 0 with this pattern, vs 3.565e7 for the
// row-major layout): elem = kt*96 + sel*32 + quad*8 + e, sel 0 = batch0
// (lane l15==0), 1 = batch1 (l15==4), 2 = permanent zero (other lanes,
// broadcast). <=2-way bank aliasing = free (m136).
// 256 blocks x 512 threads (8 waves), wave owns 32 cols (2 n-tiles),
// Wh B-frags in registers, distance-2 xproj prefetch, 4 MFMA chains,
// lgkmcnt-only barrier (no vmcnt drain on the 512-step critical path).
// ---------------------------------------------------------------------------
__global__ __launch_bounds__(512, 2) void rnn_kernel(
    const float* __restrict__ h0,   // [B][250]
    const float* __restrict__ Wh,   // [250][250]
    float* __restrict__ out)        // [B][T][250], pre-filled with xproj+bias
{
    // [buf][kt*96 + sel*32 + quad*8 + e]; 3 KB total
    __shared__ __align__(16) __bf16 hbuf[2][768];

    const int b0   = blockIdx.x * 2;
    const int tid  = threadIdx.x;
    const int lane = tid & 63;
    const int wave = tid >> 6;       // 0..7
    const int l15  = lane & 15;
    const int quad = lane >> 4;      // 0..3
    const int j0w  = wave * 32;      // 32 cols per wave

    // zero both buffers (zero slots + k>=250 padding stay 0 forever)
    for (int i = tid; i < 2 * 768; i += 512)
        ((__bf16*)hbuf)[i] = (__bf16)0.f;
    __syncthreads();

    // init h: batch0 -> sel 0, batch1 -> sel 1 slots of buffer 0
    // k -> elem: (k>>5)*96 + sel*32 + ((k>>3)&3)*8 + (k&7)
    for (int k = tid; k < H_SZ; k += 512) {
        int e = ((k >> 5) * 96) + (((k >> 3) & 3) << 3) + (k & 7);
        hbuf[0][e +  0] = (__bf16)h0[(size_t)(b0 + 0) * H_SZ + k];
        hbuf[0][e + 32] = (__bf16)h0[(size_t)(b0 + 1) * H_SZ + k];
    }

    // Wh fragments in registers: wf[tl][kt], B-frag layout
    // B[k = quad*8+e][n = l15]; n = j0w + tl*16 + l15, k = kt*32 + quad*8 + e
    bf16x8 wf[2][8];
#pragma unroll
    for (int tl = 0; tl < 2; ++tl) {
        const int j = j0w + tl * 16 + l15;
#pragma unroll
        for (int kt = 0; kt < 8; ++kt) {
            const int kb = kt * 32 + quad * 8;
            bf16x8 v;
#pragma unroll
            for (int e = 0; e < 8; ++e) {
                const int k = kb + e;
                v[e] = (j < H_SZ && k < H_SZ) ? (__bf16)Wh[(size_t)j * H_SZ + k] : (__bf16)0.f;
            }
            wf[tl][kt] = v;
        }
    }
    __syncthreads();

    // A-frag: lane l15 supplies matrix row m=l15; rows other than 0,4 must
    // be 0. l15==0 -> batch0 slot, l15==4 -> batch1 slot, else zero slot.
    const int aoff = (l15 == 0) ? 0 : ((l15 == 4) ? 32 : 64);
    const int qa   = quad & 1;           // batch select for epilogue quads 0/1

    bool   act[2];
    int    jj[2];
    int    we[2];       // hbuf write elem offset for this thread's j
    float* xptr[2];
#pragma unroll
    for (int tl = 0; tl < 2; ++tl) {
        jj[tl]  = j0w + tl * 16 + l15;
        act[tl] = (quad < 2) && (jj[tl] < H_SZ);
        const int jc = (jj[tl] < H_SZ) ? jj[tl] : 0;   // keep addr in-range
        we[tl]  = ((jc >> 5) * 96) + qa * 32 + (((jc >> 3) & 3) << 3) + (jc & 7);
        xptr[tl] = out + (size_t)(b0 + qa) * T_SZ * H_SZ + jc;
    }

    // xproj shift register: xc = step t, x1 = step t+1 (distance-2 prefetch)
    float xc[2], x1[2];
#pragma unroll
    for (int tl = 0; tl < 2; ++tl) {
        xc[tl] = act[tl] ? xptr[tl][0]    : 0.f;
        x1[tl] = act[tl] ? xptr[tl][H_SZ] : 0.f;
    }

    for (int t = 0; t < T_SZ; ++t) {
        const int cur = t & 1;
        const int nxt = cur ^ 1;

        // prefetch xproj for t+2 (in flight across ~2 full steps)
        float x2[2];
        const bool pf = (t + 2 < T_SZ);
#pragma unroll
        for (int tl = 0; tl < 2; ++tl)
            x2[tl] = (pf && act[tl]) ? xptr[tl][2 * H_SZ] : 0.f;

        // A fragments: conflict-free kt-interleaved read (16B aligned)
        bf16x8 af[8];
#pragma unroll
        for (int kt = 0; kt < 8; ++kt)
            af[kt] = *(const bf16x8*)&hbuf[cur][kt * 96 + aoff + quad * 8];

        // 4 independent accumulator chains (dep distance 4 issue slots)
        f32x4 a0a = (f32x4){0.f, 0.f, 0.f, 0.f};
        f32x4 a0b = (f32x4){0.f, 0.f, 0.f, 0.f};
        f32x4 a1a = (f32x4){0.f, 0.f, 0.f, 0.f};
        f32x4 a1b = (f32x4){0.f, 0.f, 0.f, 0.f};
#pragma unroll
        for (int kt = 0; kt < 4; ++kt) {
            a0a = __builtin_amdgcn_mfma_f32_16x16x32_bf16(af[kt],     wf[0][kt],     a0a, 0, 0, 0);
            a1a = __builtin_amdgcn_mfma_f32_16x16x32_bf16(af[kt],     wf[1][kt],     a1a, 0, 0, 0);
            a0b = __builtin_amdgcn_mfma_f32_16x16x32_bf16(af[kt + 4], wf[0][kt + 4], a0b, 0, 0, 0);
            a1b = __builtin_amdgcn_mfma_f32_16x16x32_bf16(af[kt + 4], wf[1][kt + 4], a1b, 0, 0, 0);
        }

        // epilogue: C row (m) = quad*4 + r, col (n) = lane&15
        // batch0 -> row 0 (quad0,r0), batch1 -> row 4 (quad1,r0)
        const float s[2] = { a0a[0] + a0b[0], a1a[0] + a1b[0] };
#pragma unroll
        for (int tl = 0; tl < 2; ++tl) {
            if (act[tl]) {
                float v = fast_tanh(s[tl] + xc[tl]);
                xptr[tl][0] = v;                       // overwrite xproj with state
                hbuf[nxt][we[tl]] = (__bf16)v;         // h for next step
            }
            xptr[tl] += H_SZ;
            xc[tl] = x1[tl];
            x1[tl] = x2[tl];
        }

        // end-of-step sync: LDS ops drained, barrier WITHOUT vmcnt drain
        // (prefetch loads + global stores stay in flight)
        asm volatile("s_waitcnt lgkmcnt(0)" ::: "memory");
        __builtin_amdgcn_s_barrier();
        asm volatile("" ::: "memory");
    }
}

extern "C" void kernel_launch(void* const* d_in, const int* in_sizes, int n_in,
                              void* d_out, int out_size, void* d_ws, size_t ws_size,
                              hipStream_t stream) {
    const float* x  = (const float*)d_in[0];
    const float* h  = (const float*)d_in[1];
    const float* Wx = (const float*)d_in[2];
    const float* Wh = (const float*)d_in[3];
    const float* bh = (const float*)d_in[4];
    float* out = (float*)d_out;

    const int M = B_SZ * T_SZ;                 // 262144
    xproj_kernel<<<dim3(M / XBM), dim3(256), 0, stream>>>(x, Wx, bh, out);
    rnn_kernel<<<dim3(B_SZ / 2), dim3(512), 0, stream>>>(h, Wh, out);
}